// Round 3
// baseline (671.061 us; speedup 1.0000x reference)
//
#include <hip/hip_runtime.h>

#define E_CNT 200000
#define N_CNT 50000

typedef __attribute__((ext_vector_type(8))) unsigned short ushort8;
typedef __attribute__((ext_vector_type(4))) float f32x4;
typedef __bf16 bf16x8 __attribute__((ext_vector_type(8)));

static __device__ __forceinline__ unsigned short f2bf(float f) {
  unsigned int u = __builtin_bit_cast(unsigned int, f);
  u += 0x7FFFu + ((u >> 16) & 1u);
  return (unsigned short)(u >> 16);
}

// W [K][256] f32 (row-major) -> frag-ready bf16: Bp[(kc*16 + F)*64 + lane][8]
__global__ void prep_w(const float* __restrict__ W, unsigned short* __restrict__ Bp, int KC) {
  int idx = blockIdx.x * blockDim.x + threadIdx.x;
  int total = KC * 16 * 64;
  if (idx >= total) return;
  int lane = idx & 63;
  int t = idx >> 6;
  int F = t & 15;
  int kc = t >> 4;
  int col = F * 16 + (lane & 15);
  int kb = kc * 32 + (lane >> 4) * 8;
  ushort8 v;
#pragma unroll
  for (int j = 0; j < 8; ++j) v[j] = f2bf(W[(size_t)(kb + j) * 256 + col]);
  *reinterpret_cast<ushort8*>(Bp + (size_t)idx * 8) = v;
}

// ---------- CSR build (per call, from receivers) ----------
__global__ void hist(const int* __restrict__ recv, int* __restrict__ count) {
  int e = blockIdx.x * blockDim.x + threadIdx.x;
  if (e < E_CNT) atomicAdd(&count[recv[e]], 1);
}

// one block, 1024 threads: exclusive scan of count[N_CNT] -> offs[N_CNT+1], copy to cursor
__global__ __launch_bounds__(1024) void scan_build(const int* __restrict__ count,
                                                   int* __restrict__ offs,
                                                   int* __restrict__ cursor) {
  __shared__ int part[1024];
  const int t = threadIdx.x;
  const int CH = 49;  // 1024*49 >= 50000
  const int base = t * CH;
  int s = 0;
  for (int i = 0; i < CH; ++i) {
    int idx = base + i;
    if (idx < N_CNT) s += count[idx];
  }
  part[t] = s;
  __syncthreads();
  for (int d = 1; d < 1024; d <<= 1) {
    int v = (t >= d) ? part[t - d] : 0;
    __syncthreads();
    part[t] += v;
    __syncthreads();
  }
  int run = (t == 0) ? 0 : part[t - 1];
  for (int i = 0; i < CH; ++i) {
    int idx = base + i;
    if (idx < N_CNT) {
      offs[idx] = run;
      cursor[idx] = run;
      run += count[idx];
    }
  }
  if (t == 1023) offs[N_CNT] = run;  // == E_CNT
}

__global__ void scatter(const int* __restrict__ recv, int* __restrict__ cursor,
                        int* __restrict__ eord) {
  int e = blockIdx.x * blockDim.x + threadIdx.x;
  if (e < E_CNT) {
    int pos = atomicAdd(&cursor[recv[e]], 1);
    eord[pos] = e;
  }
}

// ---------- GEMM ----------
// out[M,256] = relu(concat-input @ W + bias)
// EDGE: row e = [edges[e] | nodes[s[e]] | nodes[r[e]] | globals] (K=896), nt-store
// NODE: row n = [agg[n] | nodes[n] | globals] (K=640)
template <int NSTEPS, bool EDGE, bool PIPE>
__global__ __launch_bounds__(512) void gemm_mlp(
    const float* __restrict__ in0, const float* __restrict__ nodes,
    const float* __restrict__ gl, const int* __restrict__ senders,
    const int* __restrict__ receivers, const unsigned short* __restrict__ Bp,
    const float* __restrict__ bias, float* __restrict__ out, int M) {
  __shared__ unsigned short lds[(PIPE ? 2 : 1)][128 * 64];

  const int tid = threadIdx.x;
  const int lane = tid & 63;
  const int wave = tid >> 6;
  const int wm = wave >> 2;
  const int wn = wave & 3;
  const int row0 = blockIdx.x * 128;

  const int sr = tid >> 2;
  const int sc = tid & 3;
  int er = row0 + sr;
  if (er > M - 1) er = M - 1;

  const float* bases[4];
  if (EDGE) {
    int si = senders[er], ri = receivers[er];
    bases[0] = in0 + (size_t)er * 256;
    bases[1] = nodes + (size_t)si * 256;
    bases[2] = nodes + (size_t)ri * 256;
    bases[3] = gl;
  } else {
    bases[0] = in0 + (size_t)er * 256;
    bases[1] = nodes + (size_t)er * 256;
    bases[2] = gl;
    bases[3] = gl;
  }

  const int swz = sr & 7;
  const int wbase = sr * 64;
  const int s0 = ((sc * 2) ^ swz) * 8;
  const int s1 = ((sc * 2 + 1) ^ swz) * 8;

  f32x4 acc[4][4] = {};

  if (PIPE) {
    // ---- prologue: stage step 0 into lds[0] ----
    {
      const float4* p4 = reinterpret_cast<const float4*>(bases[0] + sc * 16);
      float fv[16];
      *reinterpret_cast<float4*>(&fv[0]) = p4[0];
      *reinterpret_cast<float4*>(&fv[4]) = p4[1];
      *reinterpret_cast<float4*>(&fv[8]) = p4[2];
      *reinterpret_cast<float4*>(&fv[12]) = p4[3];
      ushort8 w0, w1;
#pragma unroll
      for (int j = 0; j < 8; ++j) {
        w0[j] = f2bf(fv[j]);
        w1[j] = f2bf(fv[8 + j]);
      }
      *reinterpret_cast<ushort8*>(&lds[0][wbase + s0]) = w0;
      *reinterpret_cast<ushort8*>(&lds[0][wbase + s1]) = w1;
    }
    __syncthreads();

#pragma unroll
    for (int ks = 0; ks < NSTEPS; ++ks) {
      const int cc = ks & 1;

      // B-frags for this step (L2-hot) first
      bf16x8 bfr[2][4];
#pragma unroll
      for (int kk = 0; kk < 2; ++kk) {
        const int kc32 = ks * 2 + kk;
#pragma unroll
        for (int fn = 0; fn < 4; ++fn) {
          const int F = wn * 4 + fn;
          bfr[kk][fn] = __builtin_bit_cast(
              bf16x8, *reinterpret_cast<const ushort8*>(
                          Bp + ((size_t)(kc32 * 16 + F) * 64 + lane) * 8));
        }
      }

      // next-step A loads (HBM/gather)
      float4 nf0, nf1, nf2, nf3;
      if (ks + 1 < NSTEPS) {
        const float4* p4 = reinterpret_cast<const float4*>(
            bases[(ks + 1) >> 2] + ((ks + 1) & 3) * 64 + sc * 16);
        nf0 = p4[0];
        nf1 = p4[1];
        nf2 = p4[2];
        nf3 = p4[3];
      }

      // MFMA on lds[cc]
#pragma unroll
      for (int kk = 0; kk < 2; ++kk) {
        bf16x8 a[4];
#pragma unroll
        for (int fm = 0; fm < 4; ++fm) {
          int r = wm * 64 + fm * 16 + (lane & 15);
          int slot = (kk * 4 + (lane >> 4)) ^ (r & 7);
          a[fm] = __builtin_bit_cast(
              bf16x8, *reinterpret_cast<const ushort8*>(&lds[cc][r * 64 + slot * 8]));
        }
#pragma unroll
        for (int fm = 0; fm < 4; ++fm)
#pragma unroll
          for (int fn = 0; fn < 4; ++fn)
            acc[fm][fn] = __builtin_amdgcn_mfma_f32_16x16x32_bf16(
                a[fm], bfr[kk][fn], acc[fm][fn], 0, 0, 0);
      }

      // convert + write next tile
      if (ks + 1 < NSTEPS) {
        float fv[16];
        *reinterpret_cast<float4*>(&fv[0]) = nf0;
        *reinterpret_cast<float4*>(&fv[4]) = nf1;
        *reinterpret_cast<float4*>(&fv[8]) = nf2;
        *reinterpret_cast<float4*>(&fv[12]) = nf3;
        ushort8 w0, w1;
#pragma unroll
        for (int j = 0; j < 8; ++j) {
          w0[j] = f2bf(fv[j]);
          w1[j] = f2bf(fv[8 + j]);
        }
        *reinterpret_cast<ushort8*>(&lds[cc ^ 1][wbase + s0]) = w0;
        *reinterpret_cast<ushort8*>(&lds[cc ^ 1][wbase + s1]) = w1;
        __syncthreads();
      }
    }
  } else {
    // simple 2-barrier loop (round-1 structure)
#pragma unroll
    for (int ks = 0; ks < NSTEPS; ++ks) {
      const float4* p4 =
          reinterpret_cast<const float4*>(bases[ks >> 2] + (ks & 3) * 64 + sc * 16);
      float fv[16];
      *reinterpret_cast<float4*>(&fv[0]) = p4[0];
      *reinterpret_cast<float4*>(&fv[4]) = p4[1];
      *reinterpret_cast<float4*>(&fv[8]) = p4[2];
      *reinterpret_cast<float4*>(&fv[12]) = p4[3];
      ushort8 w0, w1;
#pragma unroll
      for (int j = 0; j < 8; ++j) {
        w0[j] = f2bf(fv[j]);
        w1[j] = f2bf(fv[8 + j]);
      }
      *reinterpret_cast<ushort8*>(&lds[0][wbase + s0]) = w0;
      *reinterpret_cast<ushort8*>(&lds[0][wbase + s1]) = w1;
      __syncthreads();

#pragma unroll
      for (int kk = 0; kk < 2; ++kk) {
        bf16x8 a[4];
#pragma unroll
        for (int fm = 0; fm < 4; ++fm) {
          int r = wm * 64 + fm * 16 + (lane & 15);
          int slot = (kk * 4 + (lane >> 4)) ^ (r & 7);
          a[fm] = __builtin_bit_cast(
              bf16x8, *reinterpret_cast<const ushort8*>(&lds[0][r * 64 + slot * 8]));
        }
        bf16x8 b[4];
        const int kc32 = ks * 2 + kk;
#pragma unroll
        for (int fn = 0; fn < 4; ++fn) {
          int F = wn * 4 + fn;
          b[fn] = __builtin_bit_cast(
              bf16x8, *reinterpret_cast<const ushort8*>(
                          Bp + ((size_t)(kc32 * 16 + F) * 64 + lane) * 8));
        }
#pragma unroll
        for (int fm = 0; fm < 4; ++fm)
#pragma unroll
          for (int fn = 0; fn < 4; ++fn)
            acc[fm][fn] = __builtin_amdgcn_mfma_f32_16x16x32_bf16(
                a[fm], b[fn], acc[fm][fn], 0, 0, 0);
      }
      __syncthreads();
    }
  }

  // ---- epilogue: bias + relu + store ----
  float bcol[4];
#pragma unroll
  for (int fn = 0; fn < 4; ++fn) bcol[fn] = bias[(wn * 4 + fn) * 16 + (lane & 15)];
#pragma unroll
  for (int fm = 0; fm < 4; ++fm) {
    int rb = row0 + wm * 64 + fm * 16 + ((lane >> 4) << 2);
#pragma unroll
    for (int i = 0; i < 4; ++i) {
      int gr = rb + i;
      if (gr < M) {
#pragma unroll
        for (int fn = 0; fn < 4; ++fn) {
          int col = (wn * 4 + fn) * 16 + (lane & 15);
          float v = fmaxf(acc[fm][fn][i] + bcol[fn], 0.0f);
          if (EDGE)
            __builtin_nontemporal_store(v, &out[(size_t)gr * 256 + col]);
          else
            out[(size_t)gr * 256 + col] = v;
        }
      }
    }
  }
}

// ---------- CSR segment-sum: agg[n] = sum of new_edges rows with receiver n ----------
__global__ __launch_bounds__(256) void agg_gather(const float* __restrict__ ne,
                                                  const int* __restrict__ offs,
                                                  const int* __restrict__ eord,
                                                  float* __restrict__ agg) {
  const int n = blockIdx.x;
  const int c4 = threadIdx.x & 63;
  const int g = threadIdx.x >> 6;  // 0..3
  const int o0 = offs[n], o1 = offs[n + 1];
  f32x4 s = {0.f, 0.f, 0.f, 0.f};
  for (int j = o0 + g; j < o1; j += 4) {
    int e = eord[j];
    s += *reinterpret_cast<const f32x4*>(ne + (size_t)e * 256 + c4 * 4);
  }
  __shared__ f32x4 red[256];
  red[threadIdx.x] = s;
  __syncthreads();
  if (g == 0) {
    f32x4 r = red[c4] + red[64 + c4] + red[128 + c4] + red[192 + c4];
    *reinterpret_cast<f32x4*>(agg + (size_t)n * 256 + c4 * 4) = r;
  }
}

// ---------- two-stage column sum (no atomics) ----------
__global__ void colsum_p1(const float* __restrict__ in, float* __restrict__ part, int rows) {
  const int c4 = threadIdx.x & 63;
  const int rg = threadIdx.x >> 6;
  f32x4 s = {0.f, 0.f, 0.f, 0.f};
  for (int r = blockIdx.x * 4 + rg; r < rows; r += 256)
    s += *reinterpret_cast<const f32x4*>(in + (size_t)r * 256 + c4 * 4);
  __shared__ f32x4 red[256];
  red[threadIdx.x] = s;
  __syncthreads();
  if (rg == 0) {
    f32x4 r = red[c4] + red[64 + c4] + red[128 + c4] + red[192 + c4];
    *reinterpret_cast<f32x4*>(part + (size_t)blockIdx.x * 256 + c4 * 4) = r;
  }
}

__global__ void colsum_p2(const float* __restrict__ part, float* __restrict__ out) {
  const int c = threadIdx.x;  // 256
  float s = 0.f;
  for (int p = 0; p < 64; ++p) s += part[(size_t)p * 256 + c];
  out[c] = s;
}

// new_globals = relu([esum | nsum | globals] @ Wg + bg), fp32
__global__ void global_mlp(const float* __restrict__ esum, const float* __restrict__ nsum,
                           const float* __restrict__ gl, const float* __restrict__ Wg,
                           const float* __restrict__ bg, float* __restrict__ out2) {
  __shared__ float red[512];
  int g = threadIdx.x & 127;
  int kg = threadIdx.x >> 7;
  float acc = 0.f;
  for (int k = kg; k < 640; k += 4) {
    float x = (k < 256) ? esum[k] : (k < 512 ? nsum[k - 256] : gl[k - 512]);
    acc += x * Wg[(size_t)k * 128 + g];
  }
  red[threadIdx.x] = acc;
  __syncthreads();
  if (kg == 0) {
    float r = red[g] + red[128 + g] + red[256 + g] + red[384 + g] + bg[g];
    out2[g] = fmaxf(r, 0.f);
  }
}

extern "C" void kernel_launch(void* const* d_in, const int* in_sizes, int n_in,
                              void* d_out, int out_size, void* d_ws, size_t ws_size,
                              hipStream_t stream) {
  const float* nodes = (const float*)d_in[0];
  const float* edges = (const float*)d_in[1];
  const float* gl = (const float*)d_in[2];
  const int* senders = (const int*)d_in[3];
  const int* receivers = (const int*)d_in[4];
  const float* We = (const float*)d_in[5];
  const float* be = (const float*)d_in[6];
  const float* Wn = (const float*)d_in[7];
  const float* bn = (const float*)d_in[8];
  const float* Wg = (const float*)d_in[9];
  const float* bg = (const float*)d_in[10];

  float* out0 = (float*)d_out;               // new_edges [200000,256]
  float* out1 = out0 + (size_t)E_CNT * 256;  // new_nodes [50000,256]
  float* out2 = out1 + (size_t)N_CNT * 256;  // new_globals [128]

  char* ws = (char*)d_ws;
  size_t o = 0;
  float* agg = (float*)(ws + o);            o += (size_t)N_CNT * 256 * 4;  // 51.2 MB
  float* esum = (float*)(ws + o);           o += 1024;
  float* nsum = (float*)(ws + o);           o += 1024;
  float* partE = (float*)(ws + o);          o += 64 * 256 * 4;
  float* partN = (float*)(ws + o);          o += 64 * 256 * 4;
  unsigned short* BpE = (unsigned short*)(ws + o); o += 458752;
  unsigned short* BpN = (unsigned short*)(ws + o); o += 327680;
  int* count = (int*)(ws + o);              o += 200704;
  int* offs = (int*)(ws + o);               o += 200704;  // N_CNT+1 ints
  int* cursor = (int*)(ws + o);             o += 200704;
  int* eord = (int*)(ws + o);               o += (size_t)E_CNT * 4;

  hipMemsetAsync(count, 0, (size_t)N_CNT * 4, stream);

  prep_w<<<112, 256, 0, stream>>>(We, BpE, 28);  // K=896
  prep_w<<<80, 256, 0, stream>>>(Wn, BpN, 20);   // K=640

  hist<<<(E_CNT + 255) / 256, 256, 0, stream>>>(receivers, count);
  scan_build<<<1, 1024, 0, stream>>>(count, offs, cursor);
  scatter<<<(E_CNT + 255) / 256, 256, 0, stream>>>(receivers, cursor, eord);

  gemm_mlp<14, true, true><<<(E_CNT + 127) / 128, 512, 0, stream>>>(
      edges, nodes, gl, senders, receivers, BpE, be, out0, E_CNT);

  agg_gather<<<N_CNT, 256, 0, stream>>>(out0, offs, eord, agg);

  colsum_p1<<<64, 256, 0, stream>>>(agg, partE, N_CNT);
  colsum_p2<<<1, 256, 0, stream>>>(partE, esum);

  gemm_mlp<10, false, false><<<(N_CNT + 127) / 128, 512, 0, stream>>>(
      agg, nodes, gl, nullptr, nullptr, BpN, bn, out1, N_CNT);

  colsum_p1<<<64, 256, 0, stream>>>(out1, partN, N_CNT);
  colsum_p2<<<1, 256, 0, stream>>>(partN, nsum);

  global_mlp<<<1, 512, 0, stream>>>(esum, nsum, gl, Wg, bg, out2);
}

// Round 4
// 529.499 us; speedup vs baseline: 1.2674x; 1.2674x over previous
//
#include <hip/hip_runtime.h>

#define E_CNT 200000
#define N_CNT 50000

typedef __attribute__((ext_vector_type(8))) unsigned short ushort8;
typedef __attribute__((ext_vector_type(4))) float f32x4;
typedef __bf16 bf16x8 __attribute__((ext_vector_type(8)));

static __device__ __forceinline__ unsigned short f2bf(float f) {
  unsigned int u = __builtin_bit_cast(unsigned int, f);
  u += 0x7FFFu + ((u >> 16) & 1u);
  return (unsigned short)(u >> 16);
}

// async global->LDS, 16B per lane; LDS dest = uniform base + lane*16
typedef const __attribute__((address_space(1))) void gvoid;
typedef __attribute__((address_space(3))) void lvoid;
static __device__ __forceinline__ void gload_lds16(const void* g, void* l) {
  __builtin_amdgcn_global_load_lds((gvoid*)g, (lvoid*)l, 16, 0, 0);
}

// W [K][256] f32 (row-major) -> frag-ready bf16: Bp[(kc*16 + F)*64 + lane][8]
__global__ void prep_w(const float* __restrict__ W, unsigned short* __restrict__ Bp, int KC) {
  int idx = blockIdx.x * blockDim.x + threadIdx.x;
  int total = KC * 16 * 64;
  if (idx >= total) return;
  int lane = idx & 63;
  int t = idx >> 6;
  int F = t & 15;
  int kc = t >> 4;
  int col = F * 16 + (lane & 15);
  int kb = kc * 32 + (lane >> 4) * 8;
  ushort8 v;
#pragma unroll
  for (int j = 0; j < 8; ++j) v[j] = f2bf(W[(size_t)(kb + j) * 256 + col]);
  *reinterpret_cast<ushort8*>(Bp + (size_t)idx * 8) = v;
}

// ---------- GEMM: out[M,256] = relu(concat-input @ W + bias) ----------
// EDGE: row e = [edges[e] | nodes[s[e]] | nodes[r[e]] | globals] (K=896)
//       epilogue: nt-store new_edges + atomicAdd into agg[receivers[e]]
// NODE: row n = [agg[n] | nodes[n] | globals] (K=640)
// Block: 64 rows x 256 cols, 8 waves (2x4), wave tile 32x64 (acc = 32 VGPR).
// A staged as f32 via global_load_lds (zero staging regs), double-buffered,
// XOR-swizzled via pre-swizzled SOURCE address (LDS dest stays linear).
template <int NSTEPS, bool EDGE>
__global__ __launch_bounds__(512, 4) void gemm_mlp(
    const float* __restrict__ in0, const float* __restrict__ nodes,
    const float* __restrict__ gl, const int* __restrict__ senders,
    const int* __restrict__ receivers, const unsigned short* __restrict__ Bp,
    const float* __restrict__ bias, float* __restrict__ out,
    float* __restrict__ agg, int M) {
  __shared__ float ldsA[2][64 * 64];  // 2 x 16 KB, [row][64 k-floats]

  const int tid = threadIdx.x;
  const int lane = tid & 63;
  const int wave = tid >> 6;  // 0..7
  const int wm = wave >> 2;   // 0..1 : 32-row half
  const int wn = wave & 3;    // 0..3 : 64-col quarter
  const int q = lane >> 4;    // 0..3
  const int lr = lane & 15;
  const int row0 = blockIdx.x * 64;

  // staging assignment: wave stages rows [wave*8, wave*8+8), 2 issues of 4 rows
  int rl[2];
  const float* bp[2][4];
#pragma unroll
  for (int i = 0; i < 2; ++i) {
    rl[i] = wave * 8 + i * 4 + q;
    int e = row0 + rl[i];
    if (e > M - 1) e = M - 1;
    if (EDGE) {
      bp[i][0] = in0 + (size_t)e * 256;
      bp[i][1] = nodes + (size_t)senders[e] * 256;
      bp[i][2] = nodes + (size_t)receivers[e] * 256;
      bp[i][3] = gl;
    } else {
      bp[i][0] = in0 + (size_t)e * 256;
      bp[i][1] = nodes + (size_t)e * 256;
      bp[i][2] = gl;
      bp[i][3] = gl;
    }
  }

  f32x4 acc[2][4] = {};

  // ---- prologue: stage K-step 0 into buffer 0 ----
#pragma unroll
  for (int i = 0; i < 2; ++i) {
    const float* src = bp[i][0] + ((lr ^ (rl[i] & 15)) << 2);
    gload_lds16(src, &ldsA[0][(wave * 8 + i * 4) * 64]);
  }
  __syncthreads();

#pragma unroll
  for (int ks = 0; ks < NSTEPS; ++ks) {
    const int buf = ks & 1;

    // ---- B fragments for this step (L2-hot) -- issue FIRST so their
    //      vmcnt wait doesn't drain the stage loads issued below ----
    bf16x8 bfr[2][4];
#pragma unroll
    for (int kk = 0; kk < 2; ++kk) {
      const int kc32 = ks * 2 + kk;
#pragma unroll
      for (int fn = 0; fn < 4; ++fn) {
        const int F = wn * 4 + fn;
        bfr[kk][fn] = __builtin_bit_cast(
            bf16x8, *reinterpret_cast<const ushort8*>(
                        Bp + ((size_t)(kc32 * 16 + F) * 64 + lane) * 8));
      }
    }

    // ---- async-stage next K-step into the other buffer ----
    if (ks + 1 < NSTEPS) {
      const int seg = (ks + 1) >> 2;
      const int off = ((ks + 1) & 3) * 64;
#pragma unroll
      for (int i = 0; i < 2; ++i) {
        const float* src = bp[i][seg] + off + ((lr ^ (rl[i] & 15)) << 2);
        gload_lds16(src, &ldsA[buf ^ 1][(wave * 8 + i * 4) * 64]);
      }
    }
    __builtin_amdgcn_sched_barrier(0);  // keep stage issues ahead of compute

    // ---- compute on ldsA[buf]: f32 frags -> bf16 -> MFMA ----
#pragma unroll
    for (int kk = 0; kk < 2; ++kk) {
      bf16x8 a[2];
#pragma unroll
      for (int fm = 0; fm < 2; ++fm) {
        const int r = wm * 32 + fm * 16 + lr;
        const int x = r & 15;
        const int u0 = kk * 8 + q * 2;  // 16B data unit within the 64-float row
        f32x4 lo = *reinterpret_cast<const f32x4*>(
            &ldsA[buf][r * 64 + ((u0 ^ x) << 2)]);
        f32x4 hi = *reinterpret_cast<const f32x4*>(
            &ldsA[buf][r * 64 + (((u0 + 1) ^ x) << 2)]);
        bf16x8 av;
        av[0] = (__bf16)lo[0]; av[1] = (__bf16)lo[1];
        av[2] = (__bf16)lo[2]; av[3] = (__bf16)lo[3];
        av[4] = (__bf16)hi[0]; av[5] = (__bf16)hi[1];
        av[6] = (__bf16)hi[2]; av[7] = (__bf16)hi[3];
        a[fm] = av;
      }
#pragma unroll
      for (int fm = 0; fm < 2; ++fm)
#pragma unroll
        for (int fn = 0; fn < 4; ++fn)
          acc[fm][fn] = __builtin_amdgcn_mfma_f32_16x16x32_bf16(
              a[fm], bfr[kk][fn], acc[fm][fn], 0, 0, 0);
    }
    __syncthreads();  // publishes stage(ks+1); latency hidden under compute
  }

  // ---- epilogue: bias + relu + store (+ fused segment-sum for EDGE) ----
  // D mapping: col = lane&15, row = (lane>>4)*4 + i
  float bcol[4];
#pragma unroll
  for (int fn = 0; fn < 4; ++fn) bcol[fn] = bias[wn * 64 + fn * 16 + lr];
#pragma unroll
  for (int fm = 0; fm < 2; ++fm) {
    int rb = row0 + wm * 32 + fm * 16 + q * 4;
#pragma unroll
    for (int i = 0; i < 4; ++i) {
      int gr = rb + i;
      if (gr < M) {
        int rcv = 0;
        if (EDGE) rcv = receivers[gr];
#pragma unroll
        for (int fn = 0; fn < 4; ++fn) {
          int col = wn * 64 + fn * 16 + lr;
          float v = fmaxf(acc[fm][fn][i] + bcol[fn], 0.0f);
          if (EDGE) {
            __builtin_nontemporal_store(v, &out[(size_t)gr * 256 + col]);
            atomicAdd(agg + (size_t)rcv * 256 + col, v);
          } else {
            out[(size_t)gr * 256 + col] = v;
          }
        }
      }
    }
  }
}

// ---------- two-stage column sum (no atomics) ----------
__global__ void colsum_p1(const float* __restrict__ in, float* __restrict__ part, int rows) {
  const int c4 = threadIdx.x & 63;
  const int rg = threadIdx.x >> 6;
  f32x4 s = {0.f, 0.f, 0.f, 0.f};
  for (int r = blockIdx.x * 4 + rg; r < rows; r += 256)
    s += *reinterpret_cast<const f32x4*>(in + (size_t)r * 256 + c4 * 4);
  __shared__ f32x4 red[256];
  red[threadIdx.x] = s;
  __syncthreads();
  if (rg == 0) {
    f32x4 r = red[c4] + red[64 + c4] + red[128 + c4] + red[192 + c4];
    *reinterpret_cast<f32x4*>(part + (size_t)blockIdx.x * 256 + c4 * 4) = r;
  }
}

__global__ void colsum_p2(const float* __restrict__ part, float* __restrict__ out) {
  const int c = threadIdx.x;  // 256
  float s = 0.f;
  for (int p = 0; p < 64; ++p) s += part[(size_t)p * 256 + c];
  out[c] = s;
}

// new_globals = relu([esum | nsum | globals] @ Wg + bg), fp32
__global__ void global_mlp(const float* __restrict__ esum, const float* __restrict__ nsum,
                           const float* __restrict__ gl, const float* __restrict__ Wg,
                           const float* __restrict__ bg, float* __restrict__ out2) {
  __shared__ float red[512];
  int g = threadIdx.x & 127;
  int kg = threadIdx.x >> 7;
  float acc = 0.f;
  for (int k = kg; k < 640; k += 4) {
    float x = (k < 256) ? esum[k] : (k < 512 ? nsum[k - 256] : gl[k - 512]);
    acc += x * Wg[(size_t)k * 128 + g];
  }
  red[threadIdx.x] = acc;
  __syncthreads();
  if (kg == 0) {
    float r = red[g] + red[128 + g] + red[256 + g] + red[384 + g] + bg[g];
    out2[g] = fmaxf(r, 0.f);
  }
}

extern "C" void kernel_launch(void* const* d_in, const int* in_sizes, int n_in,
                              void* d_out, int out_size, void* d_ws, size_t ws_size,
                              hipStream_t stream) {
  const float* nodes = (const float*)d_in[0];
  const float* edges = (const float*)d_in[1];
  const float* gl = (const float*)d_in[2];
  const int* senders = (const int*)d_in[3];
  const int* receivers = (const int*)d_in[4];
  const float* We = (const float*)d_in[5];
  const float* be = (const float*)d_in[6];
  const float* Wn = (const float*)d_in[7];
  const float* bn = (const float*)d_in[8];
  const float* Wg = (const float*)d_in[9];
  const float* bg = (const float*)d_in[10];

  float* out0 = (float*)d_out;               // new_edges [200000,256]
  float* out1 = out0 + (size_t)E_CNT * 256;  // new_nodes [50000,256]
  float* out2 = out1 + (size_t)N_CNT * 256;  // new_globals [128]

  char* ws = (char*)d_ws;
  size_t o = 0;
  float* agg = (float*)(ws + o);                   o += (size_t)N_CNT * 256 * 4;  // 51.2 MB
  float* esum = (float*)(ws + o);                  o += 1024;
  float* nsum = (float*)(ws + o);                  o += 1024;
  float* partE = (float*)(ws + o);                 o += 64 * 256 * 4;
  float* partN = (float*)(ws + o);                 o += 64 * 256 * 4;
  unsigned short* BpE = (unsigned short*)(ws + o); o += 458752;
  unsigned short* BpN = (unsigned short*)(ws + o); o += 327680;

  // zero agg every call (edge kernel accumulates into it atomically)
  hipMemsetAsync(agg, 0, (size_t)N_CNT * 256 * 4, stream);

  prep_w<<<112, 256, 0, stream>>>(We, BpE, 28);  // K=896
  prep_w<<<80, 256, 0, stream>>>(Wn, BpN, 20);   // K=640

  gemm_mlp<14, true><<<E_CNT / 64, 512, 0, stream>>>(
      edges, nodes, gl, senders, receivers, BpE, be, out0, agg, E_CNT);

  colsum_p1<<<64, 256, 0, stream>>>(agg, partE, N_CNT);  // colsum(agg)==colsum(new_edges)
  colsum_p2<<<1, 256, 0, stream>>>(partE, esum);

  gemm_mlp<10, false><<<(N_CNT + 63) / 64, 512, 0, stream>>>(
      agg, nodes, gl, nullptr, nullptr, BpN, bn, out1, nullptr, N_CNT);

  colsum_p1<<<64, 256, 0, stream>>>(out1, partN, N_CNT);
  colsum_p2<<<1, 256, 0, stream>>>(partN, nsum);

  global_mlp<<<1, 512, 0, stream>>>(esum, nsum, gl, Wg, bg, out2);
}